// Round 5
// baseline (85.530 us; speedup 1.0000x reference)
//
#include <hip/hip_runtime.h>
#include <stdint.h>

#define NBINS 4096
#define NB2   4096
#define CAP   32768
#define LDS_CAND 8192
#define SRATE 64        // sample every 64th point for the threshold estimate
#define UPTS  16        // points per thread in filter3 (one-shot, 12 float4s)

// Distance key: f32 bit pattern of sqrt((dx*dx + dy*dy) + dz*dz), computed with
// explicit round-to-nearest intrinsics so hipcc cannot FMA-contract and diverge
// from the numpy reference. Non-negative floats are order-isomorphic to their
// uint32 bit patterns.
__device__ __forceinline__ uint32_t dist_key(float x, float y, float z,
                                             float px, float py, float pz) {
    float dx = __fsub_rn(x, px);
    float dy = __fsub_rn(y, py);
    float dz = __fsub_rn(z, pz);
    float s = __fadd_rn(__fadd_rn(__fmul_rn(dx, dx), __fmul_rn(dy, dy)),
                        __fmul_rn(dz, dz));
    float d = __fsqrt_rn(s);
    return __float_as_uint(d);
}

__global__ void __launch_bounds__(256) zero_kernel(uint32_t* p, int n) {
    int i = blockIdx.x * 256 + threadIdx.x;
    if (i < n) p[i] = 0;
}

// Histogram of every SRATE-th point. Samples are a subset of the full set, so
// cum_sampled(<=cut) >= K  ==>  cum_full(<=cut) >= K: the cut is exact-safe.
__global__ void __launch_bounds__(256) sample_hist_kernel(const float* __restrict__ pts,
                                                          const float* __restrict__ P1,
                                                          uint32_t* __restrict__ ghist,
                                                          int nsamp) {
    __shared__ uint32_t lh[NBINS];
    for (int i = threadIdx.x; i < NBINS; i += 256) lh[i] = 0;
    __syncthreads();
    float px = P1[0], py = P1[1], pz = P1[2];
    int gid = blockIdx.x * 256 + threadIdx.x;
    int stride = gridDim.x * 256;
    for (int s = gid; s < nsamp; s += stride) {
        int i = s * SRATE;
        uint32_t k = dist_key(pts[3 * i], pts[3 * i + 1], pts[3 * i + 2], px, py, pz);
        atomicAdd(&lh[k >> 20], 1u);
    }
    __syncthreads();
    for (int i = threadIdx.x; i < NBINS; i += 256) {
        uint32_t v = lh[i];
        if (v) atomicAdd(&ghist[i], v);
    }
}

__global__ void __launch_bounds__(256) scan_kernel(const uint32_t* __restrict__ ghist,
                                                   uint32_t* __restrict__ cut, int K) {
    __shared__ uint32_t s[256];
    int t = threadIdx.x;
    uint32_t mine[16];
    uint32_t local = 0;
    for (int j = 0; j < 16; ++j) {
        mine[j] = ghist[t * 16 + j];
        local += mine[j];
    }
    s[t] = local;
    __syncthreads();
    for (int off = 1; off < 256; off <<= 1) {
        uint32_t v = (t >= off) ? s[t - off] : 0;
        __syncthreads();
        s[t] += v;
        __syncthreads();
    }
    uint32_t incl = s[t];
    uint32_t excl = incl - local;
    if (excl < (uint32_t)K && incl >= (uint32_t)K) {
        uint32_t run = excl;
        for (int j = 0; j < 16; ++j) {
            run += mine[j];
            if (run >= (uint32_t)K) {
                *cut = (uint32_t)(t * 16 + j);
                break;
            }
        }
    }
}

// One-shot max-MLP full pass: each thread owns 16 consecutive points (12
// float4s, 192 B). All 12 loads issue back-to-back from one base pointer
// (imm-offset folded), so every wave has 12 KB in flight immediately; grid
// 2048x256 puts 32 waves on every CU with zero LDS. No loop, no staging —
// pure Little's-law pressure on the memory queues.
__global__ void __launch_bounds__(256) filter3_kernel(const float* __restrict__ pts,
                                                      const float* __restrict__ P1,
                                                      const uint32_t* __restrict__ cut,
                                                      uint32_t* __restrict__ cnt,
                                                      unsigned long long* __restrict__ cand,
                                                      int ngroups, int N) {
    int g = blockIdx.x * 256 + threadIdx.x;
    const float4* p4 = (const float4*)pts;
    if (g < ngroups) {
        const float4* base = p4 + (size_t)g * 12;
        float4 v[12];
        #pragma unroll
        for (int i = 0; i < 12; ++i) v[i] = base[i];
        float px = P1[0], py = P1[1], pz = P1[2];
        uint32_t cb = *cut;
        const float* f = (const float*)v;
        uint32_t pbase = (uint32_t)g * UPTS;
        #pragma unroll
        for (int j = 0; j < UPTS; ++j) {
            uint32_t kk = dist_key(f[3 * j], f[3 * j + 1], f[3 * j + 2], px, py, pz);
            if ((kk >> 20) <= cb) {
                uint32_t pos = atomicAdd(cnt, 1u);
                if (pos < CAP) {
                    cand[pos] = ((unsigned long long)kk << 32) |
                                (unsigned long long)(pbase + j);
                }
            }
        }
    }
    // tail (N not a multiple of UPTS)
    if (blockIdx.x == 0 && threadIdx.x == 0) {
        float px = P1[0], py = P1[1], pz = P1[2];
        uint32_t cb = *cut;
        for (int i = ngroups * UPTS; i < N; ++i) {
            uint32_t kk = dist_key(pts[3 * i], pts[3 * i + 1], pts[3 * i + 2], px, py, pz);
            if ((kk >> 20) <= cb) {
                uint32_t pos = atomicAdd(cnt, 1u);
                if (pos < CAP) {
                    cand[pos] = ((unsigned long long)kk << 32) | (unsigned long long)(uint32_t)i;
                }
            }
        }
    }
}

// Single-block refine + exact select over the M candidates:
//  1. LDS histogram into NB2 linear sub-bins of [0, (cb+1)<<20) via monotone
//     multiply-shift.  2. scan -> cut2 (count(b<=cut2) >= K).  3. compact
//     qualifiers (M2 ~ K + few) to LDS + global mirror.  4. exact rank by
//     composite (key<<32)|idx — same order + tie-break as top_k(-dist).
__global__ void __launch_bounds__(1024) refine_select_kernel(
        const uint32_t* __restrict__ cnt,
        const uint32_t* __restrict__ cut,
        const unsigned long long* __restrict__ cand,
        unsigned long long* __restrict__ cand2,
        const float* __restrict__ pts,
        float* __restrict__ out, int K) {
    __shared__ uint32_t hist2[NB2];
    __shared__ uint32_t ssum[1024];
    __shared__ unsigned long long lcand[LDS_CAND];
    __shared__ uint32_t cut2_s, m2_s;
    int t = threadIdx.x;
    uint32_t M = *cnt;
    if (M > CAP) M = CAP;
    uint32_t cb = *cut;
    unsigned long long R = ((unsigned long long)(cb + 1)) << 20;
    uint32_t M32 = (uint32_t)((((unsigned long long)NB2) << 32) / R);

    for (int i = t; i < NB2; i += 1024) hist2[i] = 0;
    if (t == 0) m2_s = 0;
    __syncthreads();
    for (uint32_t i = t; i < M; i += 1024) {
        uint32_t key = (uint32_t)(cand[i] >> 32);
        uint32_t b2 = (uint32_t)(((unsigned long long)key * M32) >> 32);
        atomicAdd(&hist2[b2], 1u);
    }
    __syncthreads();

    uint32_t mine[4];
    uint32_t local = 0;
    for (int j = 0; j < 4; ++j) { mine[j] = hist2[t * 4 + j]; local += mine[j]; }
    ssum[t] = local;
    __syncthreads();
    for (int off = 1; off < 1024; off <<= 1) {
        uint32_t v = (t >= off) ? ssum[t - off] : 0;
        __syncthreads();
        ssum[t] += v;
        __syncthreads();
    }
    uint32_t incl = ssum[t], excl = incl - local;
    if (excl < (uint32_t)K && incl >= (uint32_t)K) {
        uint32_t run = excl;
        for (int j = 0; j < 4; ++j) {
            run += mine[j];
            if (run >= (uint32_t)K) { cut2_s = (uint32_t)(t * 4 + j); break; }
        }
    }
    __syncthreads();
    uint32_t c2 = cut2_s;

    for (uint32_t i = t; i < M; i += 1024) {
        unsigned long long cv = cand[i];
        uint32_t key = (uint32_t)(cv >> 32);
        uint32_t b2 = (uint32_t)(((unsigned long long)key * M32) >> 32);
        if (b2 <= c2) {
            uint32_t pos = atomicAdd(&m2_s, 1u);
            if (pos < LDS_CAND) lcand[pos] = cv;
            cand2[pos] = cv;
        }
    }
    __syncthreads();
    uint32_t M2 = m2_s;

    if (M2 <= LDS_CAND) {
        for (uint32_t i = t; i < M2; i += 1024) {
            unsigned long long ci = lcand[i];
            uint32_t rank = 0;
            for (uint32_t j = 0; j < M2; ++j) rank += (lcand[j] < ci) ? 1u : 0u;
            if (rank < (uint32_t)K) {
                uint32_t idx = (uint32_t)(ci & 0xFFFFFFFFu);
                out[3 * rank + 0] = pts[3 * idx + 0];
                out[3 * rank + 1] = pts[3 * idx + 1];
                out[3 * rank + 2] = pts[3 * idx + 2];
                out[3 * K + rank] = (float)idx;
            }
        }
    } else {
        for (uint32_t i = t; i < M2; i += 1024) {
            unsigned long long ci = cand2[i];
            uint32_t rank = 0;
            for (uint32_t j = 0; j < M2; ++j) rank += (cand2[j] < ci) ? 1u : 0u;
            if (rank < (uint32_t)K) {
                uint32_t idx = (uint32_t)(ci & 0xFFFFFFFFu);
                out[3 * rank + 0] = pts[3 * idx + 0];
                out[3 * rank + 1] = pts[3 * idx + 1];
                out[3 * rank + 2] = pts[3 * idx + 2];
                out[3 * K + rank] = (float)idx;
            }
        }
    }
}

extern "C" void kernel_launch(void* const* d_in, const int* in_sizes, int n_in,
                              void* d_out, int out_size, void* d_ws, size_t ws_size,
                              hipStream_t stream) {
    const float* pts = (const float*)d_in[0];
    const float* P1  = (const float*)d_in[1];
    float* out = (float*)d_out;

    int N = in_sizes[0] / 3;
    int ngroups = N / UPTS;
    int K = out_size / 4;  // out = K*3 coords + K indices
    int nsamp = N / SRATE;

    uint32_t* w    = (uint32_t*)d_ws;
    uint32_t* cnt  = w + 0;
    uint32_t* cut  = w + 1;
    uint32_t* hist = w + 4;                                            // NBINS
    unsigned long long* cand  = (unsigned long long*)(w + 4 + NBINS);  // CAP u64
    unsigned long long* cand2 = cand + CAP;                            // CAP u64

    int zn = 4 + NBINS;
    zero_kernel<<<(zn + 255) / 256, 256, 0, stream>>>(w, zn);
    sample_hist_kernel<<<256, 256, 0, stream>>>(pts, P1, hist, nsamp);
    scan_kernel<<<1, 256, 0, stream>>>(hist, cut, K);
    filter3_kernel<<<(ngroups + 255) / 256, 256, 0, stream>>>(pts, P1, cut, cnt, cand, ngroups, N);
    refine_select_kernel<<<1, 1024, 0, stream>>>(cnt, cut, cand, cand2, pts, out, K);
}

// Round 6
// 80.230 us; speedup vs baseline: 1.0661x; 1.0661x over previous
//
#include <hip/hip_runtime.h>
#include <stdint.h>

#define NBINS 4096
#define NB2   4096
#define CAP   32768
#define LDS_CAND 8192
#define SAMP_PTS 131072   // contiguous prefix sample for the threshold
#define CHUNK_PTS 256     // points per wave-chunk
#define CHUNK_F4  192     // float4 per wave-chunk (256*3/4)

// Distance key: f32 bit pattern of sqrt((dx*dx + dy*dy) + dz*dz), computed with
// explicit round-to-nearest intrinsics so hipcc cannot FMA-contract and diverge
// from the numpy reference. Non-negative floats are order-isomorphic to their
// uint32 bit patterns.
__device__ __forceinline__ uint32_t dist_key(float x, float y, float z,
                                             float px, float py, float pz) {
    float dx = __fsub_rn(x, px);
    float dy = __fsub_rn(y, py);
    float dz = __fsub_rn(z, pz);
    float s = __fadd_rn(__fadd_rn(__fmul_rn(dx, dx), __fmul_rn(dy, dy)),
                        __fmul_rn(dz, dz));
    float d = __fsqrt_rn(s);
    return __float_as_uint(d);
}

__global__ void __launch_bounds__(256) zero_kernel(uint32_t* p, int n) {
    int i = blockIdx.x * 256 + threadIdx.x;
    if (i < n) p[i] = 0;
}

// Histogram of the first SAMP_PTS contiguous points (i.i.d. data => same
// distribution as a strided sample). Samples are a subset of the full set, so
// cum_sampled(<=cut) >= K  ==>  cum_full(<=cut) >= K: the cut is exact-safe.
__global__ void __launch_bounds__(256) sample_hist_kernel(const float* __restrict__ pts,
                                                          const float* __restrict__ P1,
                                                          uint32_t* __restrict__ ghist,
                                                          int nsamp) {
    __shared__ uint32_t lh[NBINS];
    for (int i = threadIdx.x; i < NBINS; i += 256) lh[i] = 0;
    __syncthreads();
    float px = P1[0], py = P1[1], pz = P1[2];
    int gid = blockIdx.x * 256 + threadIdx.x;
    const float4* p4 = (const float4*)pts;
    if (gid * 4 < nsamp) {
        float4 A = p4[gid * 3 + 0];
        float4 Bv = p4[gid * 3 + 1];
        float4 Cv = p4[gid * 3 + 2];
        atomicAdd(&lh[dist_key(A.x, A.y, A.z, px, py, pz) >> 20], 1u);
        atomicAdd(&lh[dist_key(A.w, Bv.x, Bv.y, px, py, pz) >> 20], 1u);
        atomicAdd(&lh[dist_key(Bv.z, Bv.w, Cv.x, px, py, pz) >> 20], 1u);
        atomicAdd(&lh[dist_key(Cv.y, Cv.z, Cv.w, px, py, pz) >> 20], 1u);
    }
    __syncthreads();
    for (int i = threadIdx.x; i < NBINS; i += 256) {
        uint32_t v = lh[i];
        if (v) atomicAdd(&ghist[i], v);
    }
}

__global__ void __launch_bounds__(256) scan_kernel(const uint32_t* __restrict__ ghist,
                                                   uint32_t* __restrict__ cut, int K) {
    __shared__ uint32_t s[256];
    int t = threadIdx.x;
    uint32_t mine[16];
    uint32_t local = 0;
    for (int j = 0; j < 16; ++j) {
        mine[j] = ghist[t * 16 + j];
        local += mine[j];
    }
    s[t] = local;
    __syncthreads();
    for (int off = 1; off < 256; off <<= 1) {
        uint32_t v = (t >= off) ? s[t - off] : 0;
        __syncthreads();
        s[t] += v;
        __syncthreads();
    }
    uint32_t incl = s[t];
    uint32_t excl = incl - local;
    if (excl < (uint32_t)K && incl >= (uint32_t)K) {
        uint32_t run = excl;
        for (int j = 0; j < 16; ++j) {
            run += mine[j];
            if (run >= (uint32_t)K) {
                *cut = (uint32_t)(t * 16 + j);
                break;
            }
        }
    }
}

// Full pass, copy-ubench load pattern: each wave owns 192-float4 chunks; lane
// loads src[lane], src[lane+64], src[lane+128] — three perfectly coalesced
// 1 KB global_load_dwordx4 — into REGISTERS (double-buffered across chunks),
// transposes through a private per-wave LDS slice (linear b128 writes and
// 48B-stride b128 reads: both conflict-free, 0 conflicts measured in r4),
// then computes 4 points/lane. No __syncthreads; no DMA path; deep MLP like
// the 6.3 TB/s float4-copy microbenchmark.
__global__ void __launch_bounds__(256) filter5_kernel(const float* __restrict__ pts,
                                                      const float* __restrict__ P1,
                                                      const uint32_t* __restrict__ cut,
                                                      uint32_t* __restrict__ cnt,
                                                      unsigned long long* __restrict__ cand,
                                                      int nchunks, int N) {
    __shared__ float4 lds[4][CHUNK_F4];   // 12 KB: one 3 KB slice per wave
    const float4* p4 = (const float4*)pts;
    float px = P1[0], py = P1[1], pz = P1[2];
    uint32_t cb = *cut;
    int w = threadIdx.x >> 6;
    int lane = threadIdx.x & 63;
    int gw = blockIdx.x * 4 + w;
    int nw = gridDim.x * 4;

    float4 r0, r1, r2;
    int c = gw;
    if (c < nchunks) {
        const float4* s = p4 + (size_t)c * CHUNK_F4;
        r0 = s[lane]; r1 = s[lane + 64]; r2 = s[lane + 128];
    }
    for (; c < nchunks; c += nw) {
        // park current chunk in this wave's LDS slice (waits on r0..r2 loads)
        lds[w][lane] = r0;
        lds[w][lane + 64] = r1;
        lds[w][lane + 128] = r2;
        int cn = c + nw;
        if (cn < nchunks) {  // issue next chunk's loads; latency hides under
            const float4* s = p4 + (size_t)cn * CHUNK_F4;   // transpose+compute
            r0 = s[lane]; r1 = s[lane + 64]; r2 = s[lane + 128];
        }
        asm volatile("s_waitcnt lgkmcnt(0)" ::: "memory");  // writes -> reads
        const float* fb = (const float*)&lds[w][0] + lane * 12;
        float4 A  = *(const float4*)(fb);
        float4 Bv = *(const float4*)(fb + 4);
        float4 Cv = *(const float4*)(fb + 8);
        uint32_t kk[4];
        kk[0] = dist_key(A.x, A.y, A.z, px, py, pz);
        kk[1] = dist_key(A.w, Bv.x, Bv.y, px, py, pz);
        kk[2] = dist_key(Bv.z, Bv.w, Cv.x, px, py, pz);
        kk[3] = dist_key(Cv.y, Cv.z, Cv.w, px, py, pz);
        uint32_t pbase = (uint32_t)c * CHUNK_PTS + (uint32_t)lane * 4;
        #pragma unroll
        for (int j = 0; j < 4; ++j) {
            if ((kk[j] >> 20) <= cb) {
                uint32_t pos = atomicAdd(cnt, 1u);
                if (pos < CAP) {
                    cand[pos] = ((unsigned long long)kk[j] << 32) |
                                (unsigned long long)(pbase + j);
                }
            }
        }
    }
    // tail (N not a multiple of CHUNK_PTS) — empty for N = 2^23
    if (blockIdx.x == 0 && threadIdx.x == 0) {
        for (int i = nchunks * CHUNK_PTS; i < N; ++i) {
            uint32_t kk = dist_key(pts[3 * i], pts[3 * i + 1], pts[3 * i + 2], px, py, pz);
            if ((kk >> 20) <= cb) {
                uint32_t pos = atomicAdd(cnt, 1u);
                if (pos < CAP) {
                    cand[pos] = ((unsigned long long)kk << 32) | (unsigned long long)(uint32_t)i;
                }
            }
        }
    }
}

// Single-block refine + exact select over the M candidates:
//  1. LDS histogram into NB2 linear sub-bins of [0, (cb+1)<<20) via monotone
//     multiply-shift.  2. scan -> cut2 (count(b<=cut2) >= K).  3. compact
//     qualifiers (M2 ~ K + few) to LDS + global mirror.  4. exact rank by
//     composite (key<<32)|idx — same order + tie-break as top_k(-dist).
__global__ void __launch_bounds__(1024) refine_select_kernel(
        const uint32_t* __restrict__ cnt,
        const uint32_t* __restrict__ cut,
        const unsigned long long* __restrict__ cand,
        unsigned long long* __restrict__ cand2,
        const float* __restrict__ pts,
        float* __restrict__ out, int K) {
    __shared__ uint32_t hist2[NB2];
    __shared__ uint32_t ssum[1024];
    __shared__ unsigned long long lcand[LDS_CAND];
    __shared__ uint32_t cut2_s, m2_s;
    int t = threadIdx.x;
    uint32_t M = *cnt;
    if (M > CAP) M = CAP;
    uint32_t cb = *cut;
    unsigned long long R = ((unsigned long long)(cb + 1)) << 20;
    uint32_t M32 = (uint32_t)((((unsigned long long)NB2) << 32) / R);

    for (int i = t; i < NB2; i += 1024) hist2[i] = 0;
    if (t == 0) m2_s = 0;
    __syncthreads();
    for (uint32_t i = t; i < M; i += 1024) {
        uint32_t key = (uint32_t)(cand[i] >> 32);
        uint32_t b2 = (uint32_t)(((unsigned long long)key * M32) >> 32);
        atomicAdd(&hist2[b2], 1u);
    }
    __syncthreads();

    uint32_t mine[4];
    uint32_t local = 0;
    for (int j = 0; j < 4; ++j) { mine[j] = hist2[t * 4 + j]; local += mine[j]; }
    ssum[t] = local;
    __syncthreads();
    for (int off = 1; off < 1024; off <<= 1) {
        uint32_t v = (t >= off) ? ssum[t - off] : 0;
        __syncthreads();
        ssum[t] += v;
        __syncthreads();
    }
    uint32_t incl = ssum[t], excl = incl - local;
    if (excl < (uint32_t)K && incl >= (uint32_t)K) {
        uint32_t run = excl;
        for (int j = 0; j < 4; ++j) {
            run += mine[j];
            if (run >= (uint32_t)K) { cut2_s = (uint32_t)(t * 4 + j); break; }
        }
    }
    __syncthreads();
    uint32_t c2 = cut2_s;

    for (uint32_t i = t; i < M; i += 1024) {
        unsigned long long cv = cand[i];
        uint32_t key = (uint32_t)(cv >> 32);
        uint32_t b2 = (uint32_t)(((unsigned long long)key * M32) >> 32);
        if (b2 <= c2) {
            uint32_t pos = atomicAdd(&m2_s, 1u);
            if (pos < LDS_CAND) lcand[pos] = cv;
            cand2[pos] = cv;
        }
    }
    __syncthreads();
    uint32_t M2 = m2_s;

    if (M2 <= LDS_CAND) {
        for (uint32_t i = t; i < M2; i += 1024) {
            unsigned long long ci = lcand[i];
            uint32_t rank = 0;
            for (uint32_t j = 0; j < M2; ++j) rank += (lcand[j] < ci) ? 1u : 0u;
            if (rank < (uint32_t)K) {
                uint32_t idx = (uint32_t)(ci & 0xFFFFFFFFu);
                out[3 * rank + 0] = pts[3 * idx + 0];
                out[3 * rank + 1] = pts[3 * idx + 1];
                out[3 * rank + 2] = pts[3 * idx + 2];
                out[3 * K + rank] = (float)idx;
            }
        }
    } else {
        for (uint32_t i = t; i < M2; i += 1024) {
            unsigned long long ci = cand2[i];
            uint32_t rank = 0;
            for (uint32_t j = 0; j < M2; ++j) rank += (cand2[j] < ci) ? 1u : 0u;
            if (rank < (uint32_t)K) {
                uint32_t idx = (uint32_t)(ci & 0xFFFFFFFFu);
                out[3 * rank + 0] = pts[3 * idx + 0];
                out[3 * rank + 1] = pts[3 * idx + 1];
                out[3 * rank + 2] = pts[3 * idx + 2];
                out[3 * K + rank] = (float)idx;
            }
        }
    }
}

extern "C" void kernel_launch(void* const* d_in, const int* in_sizes, int n_in,
                              void* d_out, int out_size, void* d_ws, size_t ws_size,
                              hipStream_t stream) {
    const float* pts = (const float*)d_in[0];
    const float* P1  = (const float*)d_in[1];
    float* out = (float*)d_out;

    int N = in_sizes[0] / 3;
    int nchunks = N / CHUNK_PTS;
    int K = out_size / 4;  // out = K*3 coords + K indices
    int nsamp = (N < SAMP_PTS) ? (N / 4) * 4 : SAMP_PTS;

    uint32_t* w    = (uint32_t*)d_ws;
    uint32_t* cnt  = w + 0;
    uint32_t* cut  = w + 1;
    uint32_t* hist = w + 4;                                            // NBINS
    unsigned long long* cand  = (unsigned long long*)(w + 4 + NBINS);  // CAP u64
    unsigned long long* cand2 = cand + CAP;                            // CAP u64

    int zn = 4 + NBINS;
    zero_kernel<<<(zn + 255) / 256, 256, 0, stream>>>(w, zn);
    sample_hist_kernel<<<(nsamp / 4 + 255) / 256, 256, 0, stream>>>(pts, P1, hist, nsamp);
    scan_kernel<<<1, 256, 0, stream>>>(hist, cut, K);
    filter5_kernel<<<2048, 256, 0, stream>>>(pts, P1, cut, cnt, cand, nchunks, N);
    refine_select_kernel<<<1, 1024, 0, stream>>>(cnt, cut, cand, cand2, pts, out, K);
}

// Round 7
// 45.159 us; speedup vs baseline: 1.8940x; 1.7766x over previous
//
#include <hip/hip_runtime.h>
#include <stdint.h>

#define NBINS 4096
#define NB2   4096
#define NBLK  2048        // filter blocks = slot regions
#define SLOT  16          // candidate slots per block (expected ~2 hits)
#define OVF_CAP 8192
#define LDS_CAND 8192
#define SAMP_PTS 131072   // contiguous prefix sample for the threshold
#define CHUNK_PTS 256     // points per wave-chunk
#define CHUNK_F4  192     // float4 per wave-chunk (256*3/4)

// Distance key: f32 bit pattern of sqrt((dx*dx + dy*dy) + dz*dz), computed with
// explicit round-to-nearest intrinsics so hipcc cannot FMA-contract and diverge
// from the numpy reference. Non-negative floats are order-isomorphic to their
// uint32 bit patterns.
__device__ __forceinline__ uint32_t dist_key(float x, float y, float z,
                                             float px, float py, float pz) {
    float dx = __fsub_rn(x, px);
    float dy = __fsub_rn(y, py);
    float dz = __fsub_rn(z, pz);
    float s = __fadd_rn(__fadd_rn(__fmul_rn(dx, dx), __fmul_rn(dy, dy)),
                        __fmul_rn(dz, dz));
    float d = __fsqrt_rn(s);
    return __float_as_uint(d);
}

// Histogram of the first SAMP_PTS contiguous points (i.i.d. data => same
// distribution as a strided sample). Samples are a subset of the full set, so
// cum_sampled(<=cut) >= K  ==>  cum_full(<=cut) >= K: the cut is exact-safe.
__global__ void __launch_bounds__(256) sample_hist_kernel(const float* __restrict__ pts,
                                                          const float* __restrict__ P1,
                                                          uint32_t* __restrict__ ghist,
                                                          int nsamp) {
    __shared__ uint32_t lh[NBINS];
    for (int i = threadIdx.x; i < NBINS; i += 256) lh[i] = 0;
    __syncthreads();
    float px = P1[0], py = P1[1], pz = P1[2];
    int gid = blockIdx.x * 256 + threadIdx.x;
    const float4* p4 = (const float4*)pts;
    if (gid * 4 < nsamp) {
        float4 A = p4[gid * 3 + 0];
        float4 Bv = p4[gid * 3 + 1];
        float4 Cv = p4[gid * 3 + 2];
        atomicAdd(&lh[dist_key(A.x, A.y, A.z, px, py, pz) >> 20], 1u);
        atomicAdd(&lh[dist_key(A.w, Bv.x, Bv.y, px, py, pz) >> 20], 1u);
        atomicAdd(&lh[dist_key(Bv.z, Bv.w, Cv.x, px, py, pz) >> 20], 1u);
        atomicAdd(&lh[dist_key(Cv.y, Cv.z, Cv.w, px, py, pz) >> 20], 1u);
    }
    __syncthreads();
    for (int i = threadIdx.x; i < NBINS; i += 256) {
        uint32_t v = lh[i];
        if (v) atomicAdd(&ghist[i], v);
    }
}

__global__ void __launch_bounds__(256) scan_kernel(const uint32_t* __restrict__ ghist,
                                                   uint32_t* __restrict__ cut, int K) {
    __shared__ uint32_t s[256];
    int t = threadIdx.x;
    uint32_t mine[16];
    uint32_t local = 0;
    for (int j = 0; j < 16; ++j) {
        mine[j] = ghist[t * 16 + j];
        local += mine[j];
    }
    s[t] = local;
    __syncthreads();
    for (int off = 1; off < 256; off <<= 1) {
        uint32_t v = (t >= off) ? s[t - off] : 0;
        __syncthreads();
        s[t] += v;
        __syncthreads();
    }
    uint32_t incl = s[t];
    uint32_t excl = incl - local;
    if (excl < (uint32_t)K && incl >= (uint32_t)K) {
        uint32_t run = excl;
        for (int j = 0; j < 16; ++j) {
            run += mine[j];
            if (run >= (uint32_t)K) {
                *cut = (uint32_t)(t * 16 + j);
                break;
            }
        }
    }
}

// Full pass with ZERO global atomics on the common path. Read side identical
// to round 5 (copy-ubench coalesced loads + conflict-free LDS transpose).
// Hits (expected ~2 per block) append to an LDS buffer via block-local LDS
// atomics; at block end the buffer flushes to this block's PRIVATE slot
// region gslots[b*SLOT..] + gcount[b]. Only pathological overflow (>SLOT hits
// in one block, P~1e-10 here) touches the global ovf counter.
__global__ void __launch_bounds__(256) filter6_kernel(const float* __restrict__ pts,
                                                      const float* __restrict__ P1,
                                                      const uint32_t* __restrict__ cut,
                                                      unsigned long long* __restrict__ gslots,
                                                      uint32_t* __restrict__ gcount,
                                                      uint32_t* __restrict__ ovf_cnt,
                                                      unsigned long long* __restrict__ ovf,
                                                      int nchunks, int N) {
    __shared__ float4 park[4][CHUNK_F4];     // 12 KB: one 3 KB slice per wave
    __shared__ unsigned long long lhits[SLOT];
    __shared__ uint32_t lcnt;
    if (threadIdx.x == 0) lcnt = 0;
    __syncthreads();

    const float4* p4 = (const float4*)pts;
    float px = P1[0], py = P1[1], pz = P1[2];
    uint32_t cb = *cut;
    int w = threadIdx.x >> 6;
    int lane = threadIdx.x & 63;
    int b = blockIdx.x;
    int cpb = (nchunks + NBLK - 1) / NBLK;       // chunks per block
    int cbeg = b * cpb;
    int cend = cbeg + cpb; if (cend > nchunks) cend = nchunks;

    float4 r0, r1, r2;
    int c = cbeg + w;
    if (c < cend) {
        const float4* s = p4 + (size_t)c * CHUNK_F4;
        r0 = s[lane]; r1 = s[lane + 64]; r2 = s[lane + 128];
    }
    for (; c < cend; c += 4) {
        park[w][lane] = r0;
        park[w][lane + 64] = r1;
        park[w][lane + 128] = r2;
        int cn = c + 4;
        if (cn < cend) {   // prefetch next chunk; latency hides under compute
            const float4* s = p4 + (size_t)cn * CHUNK_F4;
            r0 = s[lane]; r1 = s[lane + 64]; r2 = s[lane + 128];
        }
        asm volatile("s_waitcnt lgkmcnt(0)" ::: "memory");
        const float* fb = (const float*)&park[w][0] + lane * 12;
        float4 A  = *(const float4*)(fb);
        float4 Bv = *(const float4*)(fb + 4);
        float4 Cv = *(const float4*)(fb + 8);
        uint32_t kk[4];
        kk[0] = dist_key(A.x, A.y, A.z, px, py, pz);
        kk[1] = dist_key(A.w, Bv.x, Bv.y, px, py, pz);
        kk[2] = dist_key(Bv.z, Bv.w, Cv.x, px, py, pz);
        kk[3] = dist_key(Cv.y, Cv.z, Cv.w, px, py, pz);
        uint32_t pbase = (uint32_t)c * CHUNK_PTS + (uint32_t)lane * 4;
        #pragma unroll
        for (int j = 0; j < 4; ++j) {
            if ((kk[j] >> 20) <= cb) {
                unsigned long long cv = ((unsigned long long)kk[j] << 32) |
                                        (unsigned long long)(pbase + j);
                uint32_t pos = atomicAdd(&lcnt, 1u);
                if (pos < SLOT) {
                    lhits[pos] = cv;
                } else {
                    uint32_t op = atomicAdd(ovf_cnt, 1u);
                    if (op < OVF_CAP) ovf[op] = cv;
                }
            }
        }
    }
    // tail (N not a multiple of CHUNK_PTS): last block, thread 0
    if (b == NBLK - 1 && threadIdx.x == 0) {
        for (int i = nchunks * CHUNK_PTS; i < N; ++i) {
            uint32_t kk = dist_key(pts[3 * i], pts[3 * i + 1], pts[3 * i + 2], px, py, pz);
            if ((kk >> 20) <= cb) {
                unsigned long long cv = ((unsigned long long)kk << 32) |
                                        (unsigned long long)(uint32_t)i;
                uint32_t pos = atomicAdd(&lcnt, 1u);
                if (pos < SLOT) {
                    lhits[pos] = cv;
                } else {
                    uint32_t op = atomicAdd(ovf_cnt, 1u);
                    if (op < OVF_CAP) ovf[op] = cv;
                }
            }
        }
    }
    __syncthreads();
    uint32_t n = lcnt; if (n > SLOT) n = SLOT;
    if (threadIdx.x < n) gslots[(size_t)b * SLOT + threadIdx.x] = lhits[threadIdx.x];
    if (threadIdx.x == 0) gcount[b] = n;
}

// Single-block refine + exact select, iterating slot space directly:
//  1. LDS histogram of candidate keys into NB2 linear sub-bins of
//     [0, (cb+1)<<20) via monotone multiply-shift.  2. scan -> cut2
//     (count(b<=cut2) >= K).  3. compact qualifiers (M2 ~ K + few) to LDS
//     (+ global mirror).  4. exact rank by composite (key<<32)|idx — same
//     order + tie-break as top_k(-dist).
__global__ void __launch_bounds__(1024) refine_select_kernel(
        const uint32_t* __restrict__ gcount,
        const unsigned long long* __restrict__ gslots,
        const uint32_t* __restrict__ ovf_cnt,
        const unsigned long long* __restrict__ ovf,
        const uint32_t* __restrict__ cut,
        unsigned long long* __restrict__ cand2,
        const float* __restrict__ pts,
        float* __restrict__ out, int K) {
    __shared__ uint32_t hist2[NB2];
    __shared__ uint32_t ssum[1024];
    __shared__ unsigned long long lcand[LDS_CAND];
    __shared__ uint32_t cut2_s, m2_s;
    int t = threadIdx.x;
    uint32_t cb = *cut;
    unsigned long long R = ((unsigned long long)(cb + 1)) << 20;
    uint32_t M32 = (uint32_t)((((unsigned long long)NB2) << 32) / R);
    uint32_t novf = *ovf_cnt; if (novf > OVF_CAP) novf = OVF_CAP;

    for (int i = t; i < NB2; i += 1024) hist2[i] = 0;
    if (t == 0) m2_s = 0;
    __syncthreads();
    for (int b = t; b < NBLK; b += 1024) {
        uint32_t n = gcount[b];
        for (uint32_t j = 0; j < n; ++j) {
            uint32_t key = (uint32_t)(gslots[(size_t)b * SLOT + j] >> 32);
            atomicAdd(&hist2[(uint32_t)(((unsigned long long)key * M32) >> 32)], 1u);
        }
    }
    for (uint32_t i = t; i < novf; i += 1024) {
        uint32_t key = (uint32_t)(ovf[i] >> 32);
        atomicAdd(&hist2[(uint32_t)(((unsigned long long)key * M32) >> 32)], 1u);
    }
    __syncthreads();

    uint32_t mine[4];
    uint32_t local = 0;
    for (int j = 0; j < 4; ++j) { mine[j] = hist2[t * 4 + j]; local += mine[j]; }
    ssum[t] = local;
    __syncthreads();
    for (int off = 1; off < 1024; off <<= 1) {
        uint32_t v = (t >= off) ? ssum[t - off] : 0;
        __syncthreads();
        ssum[t] += v;
        __syncthreads();
    }
    uint32_t incl = ssum[t], excl = incl - local;
    if (excl < (uint32_t)K && incl >= (uint32_t)K) {
        uint32_t run = excl;
        for (int j = 0; j < 4; ++j) {
            run += mine[j];
            if (run >= (uint32_t)K) { cut2_s = (uint32_t)(t * 4 + j); break; }
        }
    }
    __syncthreads();
    uint32_t c2 = cut2_s;

    for (int b = t; b < NBLK; b += 1024) {
        uint32_t n = gcount[b];
        for (uint32_t j = 0; j < n; ++j) {
            unsigned long long cv = gslots[(size_t)b * SLOT + j];
            uint32_t key = (uint32_t)(cv >> 32);
            if ((uint32_t)(((unsigned long long)key * M32) >> 32) <= c2) {
                uint32_t pos = atomicAdd(&m2_s, 1u);
                if (pos < LDS_CAND) lcand[pos] = cv;
                cand2[pos] = cv;
            }
        }
    }
    for (uint32_t i = t; i < novf; i += 1024) {
        unsigned long long cv = ovf[i];
        uint32_t key = (uint32_t)(cv >> 32);
        if ((uint32_t)(((unsigned long long)key * M32) >> 32) <= c2) {
            uint32_t pos = atomicAdd(&m2_s, 1u);
            if (pos < LDS_CAND) lcand[pos] = cv;
            cand2[pos] = cv;
        }
    }
    __syncthreads();
    uint32_t M2 = m2_s;

    if (M2 <= LDS_CAND) {
        for (uint32_t i = t; i < M2; i += 1024) {
            unsigned long long ci = lcand[i];
            uint32_t rank = 0;
            for (uint32_t j = 0; j < M2; ++j) rank += (lcand[j] < ci) ? 1u : 0u;
            if (rank < (uint32_t)K) {
                uint32_t idx = (uint32_t)(ci & 0xFFFFFFFFu);
                out[3 * rank + 0] = pts[3 * idx + 0];
                out[3 * rank + 1] = pts[3 * idx + 1];
                out[3 * rank + 2] = pts[3 * idx + 2];
                out[3 * K + rank] = (float)idx;
            }
        }
    } else {
        for (uint32_t i = t; i < M2; i += 1024) {
            unsigned long long ci = cand2[i];
            uint32_t rank = 0;
            for (uint32_t j = 0; j < M2; ++j) rank += (cand2[j] < ci) ? 1u : 0u;
            if (rank < (uint32_t)K) {
                uint32_t idx = (uint32_t)(ci & 0xFFFFFFFFu);
                out[3 * rank + 0] = pts[3 * idx + 0];
                out[3 * rank + 1] = pts[3 * idx + 1];
                out[3 * rank + 2] = pts[3 * idx + 2];
                out[3 * K + rank] = (float)idx;
            }
        }
    }
}

extern "C" void kernel_launch(void* const* d_in, const int* in_sizes, int n_in,
                              void* d_out, int out_size, void* d_ws, size_t ws_size,
                              hipStream_t stream) {
    const float* pts = (const float*)d_in[0];
    const float* P1  = (const float*)d_in[1];
    float* out = (float*)d_out;

    int N = in_sizes[0] / 3;
    int nchunks = N / CHUNK_PTS;
    int K = out_size / 4;  // out = K*3 coords + K indices
    int nsamp = (N < SAMP_PTS) ? (N / 4) * 4 : SAMP_PTS;

    uint32_t* w       = (uint32_t*)d_ws;
    uint32_t* ovf_cnt = w + 0;
    uint32_t* cut     = w + 1;
    uint32_t* hist    = w + 4;                          // NBINS
    uint32_t* gcount  = w + 4 + NBINS;                  // NBLK
    unsigned long long* gslots = (unsigned long long*)(w + 4 + NBINS + NBLK); // NBLK*SLOT
    unsigned long long* ovf    = gslots + (size_t)NBLK * SLOT;                // OVF_CAP
    unsigned long long* cand2  = ovf + OVF_CAP;                               // LDS_CAND mirror

    // zero: ovf_cnt, (cut — rewritten by scan), hist, gcount
    hipMemsetAsync(w, 0, (size_t)(4 + NBINS + NBLK) * sizeof(uint32_t), stream);
    sample_hist_kernel<<<(nsamp / 4 + 255) / 256, 256, 0, stream>>>(pts, P1, hist, nsamp);
    scan_kernel<<<1, 256, 0, stream>>>(hist, cut, K);
    filter6_kernel<<<NBLK, 256, 0, stream>>>(pts, P1, cut, gslots, gcount, ovf_cnt, ovf, nchunks, N);
    refine_select_kernel<<<1, 1024, 0, stream>>>(gcount, gslots, ovf_cnt, ovf, cut,
                                                 cand2, pts, out, K);
}